// Round 10
// baseline (527.618 us; speedup 1.0000x reference)
//
#include <hip/hip_runtime.h>

#define N_NODES 50000
#define E_EDGES 800000
#define IN_F 256
#define H_F 128
#define C_OUT 10
#define NBKT ((N_NODES + 63) / 64)        // 782 coarse buckets (64 nodes each)
static_assert(NBKT <= 1024, "scanB single block assumes <=1024 buckets");

typedef __attribute__((ext_vector_type(4))) float f32x4;
typedef __attribute__((ext_vector_type(8))) short s16x8;

__device__ __forceinline__ unsigned short f2bf_rne(float x) {
    unsigned u = __float_as_uint(x);
    u = (u + 0x7FFFu + ((u >> 16) & 1u)) >> 16;
    return (unsigned short)u;
}
__device__ __forceinline__ float bf2f(unsigned short h) {
    return __uint_as_float(((unsigned)h) << 16);
}

// ---------------- CSR build: coarse-bucket counting sort ----------------

// count edges per 64-node bucket
__global__ __launch_bounds__(256) void k_bcount(const int* __restrict__ dst,
                                                int* __restrict__ bcnt) {
    int e = blockIdx.x * 256 + threadIdx.x;
    if (e < E_EDGES) atomicAdd(&bcnt[dst[e] >> 6], 1);
}

// single-block exclusive scan of bucket counts; init bucket cursors
__global__ __launch_bounds__(1024) void k_scanB(const int* __restrict__ bcnt,
                                                int* __restrict__ boff,
                                                int* __restrict__ bcur) {
    __shared__ int sm[1024];
    int tid = threadIdx.x;
    int v = (tid < NBKT) ? bcnt[tid] : 0;
    sm[tid] = v;
    __syncthreads();
#pragma unroll
    for (int off = 1; off < 1024; off <<= 1) {
        int t = (tid >= off) ? sm[tid - off] : 0;
        __syncthreads();
        sm[tid] += t;
        __syncthreads();
    }
    if (tid < NBKT) {
        int ex = sm[tid] - v;
        boff[tid] = ex;
        bcur[tid] = ex;
    }
    if (tid == 0) boff[NBKT] = E_EDGES;
}

// pass A: scatter edges into coarse bucket regions, packed (src<<6)|dstLocal.
// Each bucket region fills densely -> L2 coalesces to full-line HBM writes.
__global__ __launch_bounds__(256) void k_passA(const int* __restrict__ src,
                                               const int* __restrict__ dst,
                                               int* __restrict__ bcur,
                                               int* __restrict__ packed) {
    int e = blockIdx.x * 256 + threadIdx.x;
    if (e >= E_EDGES) return;
    int s = src[e], d = dst[e];
    int pos = atomicAdd(&bcur[d >> 6], 1);
    packed[pos] = (s << 6) | (d & 63);
}

// pass B: per-bucket fine sort in LDS; emits csr_src (writes stay within the
// bucket's ~4KB L2-resident region) plus cnt/row_off/dinv as by-products.
__global__ __launch_bounds__(256) void k_passB(const int* __restrict__ packed,
                                               const int* __restrict__ boff,
                                               int* __restrict__ cnt,
                                               int* __restrict__ row_off,
                                               float* __restrict__ dinv,
                                               int* __restrict__ csr_src) {
    __shared__ int hist[64], loff[64], lcur[64];
    const int b = blockIdx.x, tid = threadIdx.x;
    const int beg = boff[b], end = boff[b + 1];
    if (tid < 64) hist[tid] = 0;
    __syncthreads();
    for (int e = beg + tid; e < end; e += 256)
        atomicAdd(&hist[packed[e] & 63], 1);
    __syncthreads();
    if (tid == 0) {
        int run = 0;
#pragma unroll
        for (int i = 0; i < 64; ++i) { int t = hist[i]; loff[i] = run; lcur[i] = run; run += t; }
    }
    __syncthreads();
    if (tid < 64) {
        int node = b * 64 + tid;
        if (node < N_NODES) {
            int c = hist[tid];
            cnt[node] = c;
            dinv[node] = rsqrtf((float)(c + 1));
            row_off[node] = beg + loff[tid];
        }
    }
    for (int e = beg + tid; e < end; e += 256) {
        int p = packed[e];
        int pos = atomicAdd(&lcur[p & 63], 1);
        csr_src[beg + pos] = p >> 6;
    }
}

// ---------------- pre-pack W1/W2 into MFMA fragment-image (bf16 hi/lo) -------
// Fragment image: [kt][nb][lane][j] ushort, lane=(n&15)+16*((k&31)>>3), j=k&7.

__global__ __launch_bounds__(256) void k_convB(const float* __restrict__ W1,
                                               const float* __restrict__ W2,
                                               unsigned short* __restrict__ B1h,
                                               unsigned short* __restrict__ B1l,
                                               unsigned short* __restrict__ B2h,
                                               unsigned short* __restrict__ B2l) {
    int id = blockIdx.x * 256 + threadIdx.x;
    const float* W;
    unsigned short *Bh, *Bl;
    int k, n;
    if (id < IN_F * H_F) {
        W = W1; Bh = B1h; Bl = B1l;
        k = id >> 7; n = id & 127;
    } else {
        id -= IN_F * H_F;
        if (id >= H_F * H_F) return;
        W = W2; Bh = B2h; Bl = B2l;
        k = id >> 7; n = id & 127;
    }
    float x = W[(size_t)k * H_F + n];
    unsigned short h = f2bf_rne(x);
    unsigned short l = f2bf_rne(x - bf2f(h));
    int kt = k >> 5, kg = (k & 31) >> 3, j = k & 7;
    int lane = (n & 15) + 16 * kg, nb = n >> 4;
    size_t idx = (((size_t)kt * 8 + nb) * 64 + lane) * 8 + j;
    Bh[idx] = h;
    Bl[idx] = l;
}

// ---------------- MFMA GEMM: tab[M x 128] = bf16((A[M x K] @ W[K x 128])*dinv) --
// bf16x3 split (hi*hi + hi*lo + lo*hi), fp32 accumulate. 128x128 tile,
// 4 waves x (2 m-frags x 8 n-frags), BK=32. Output is the bf16 gather table.

template <int K>
__global__ __launch_bounds__(256) void k_gemm_mfma(const float* __restrict__ A,
                                                   const unsigned short* __restrict__ Bh_img,
                                                   const unsigned short* __restrict__ Bl_img,
                                                   const float* __restrict__ dinv,
                                                   unsigned short* __restrict__ tab) {
    __shared__ unsigned short Ah[8 * 64 * 8];   // [mb][lane][j]
    __shared__ unsigned short Al[8 * 64 * 8];
    __shared__ unsigned short Bh[8 * 64 * 8];   // [nb][lane][j]
    __shared__ unsigned short Bl[8 * 64 * 8];

    const int tid  = threadIdx.x;
    const int w    = tid >> 6;
    const int lane = tid & 63;
    const int brow = blockIdx.x * 128;

    const int ar  = tid >> 1;          // A-stage row 0..127
    const int akq = tid & 1;           // k-half (16 floats)
    const int arow_l = min(brow + ar, N_NODES - 1);
    const float* Arow = A + (size_t)arow_l * K;
    const int amb = ar >> 4;
    const int ar15 = ar & 15;

    f32x4 acc[2][8] = {};

    for (int kt = 0; kt < K; kt += 32) {
        // stage A: 4x float4 per thread, convert to bf16 hi/lo
#pragma unroll
        for (int i = 0; i < 4; ++i) {
            int k0 = akq * 16 + i * 4;           // 0..28, step 4
            float4 v = *(const float4*)(Arow + kt + k0);
            unsigned short h0 = f2bf_rne(v.x), h1 = f2bf_rne(v.y);
            unsigned short h2 = f2bf_rne(v.z), h3 = f2bf_rne(v.w);
            unsigned short l0 = f2bf_rne(v.x - bf2f(h0));
            unsigned short l1 = f2bf_rne(v.y - bf2f(h1));
            unsigned short l2 = f2bf_rne(v.z - bf2f(h2));
            unsigned short l3 = f2bf_rne(v.w - bf2f(h3));
            int kg = k0 >> 3, j0 = k0 & 7;       // j0 in {0,4}
            int idx = ((amb * 64) + ar15 + 16 * kg) * 8 + j0;
            *(uint2*)&Ah[idx] = make_uint2((unsigned)h0 | ((unsigned)h1 << 16),
                                           (unsigned)h2 | ((unsigned)h3 << 16));
            *(uint2*)&Al[idx] = make_uint2((unsigned)l0 | ((unsigned)l1 << 16),
                                           (unsigned)l2 | ((unsigned)l3 << 16));
        }
        // stage B: copy 8 KB hi + 8 KB lo from pre-packed image
        {
            const uint4* sh = (const uint4*)(Bh_img + (size_t)(kt >> 5) * 4096);
            const uint4* sl = (const uint4*)(Bl_img + (size_t)(kt >> 5) * 4096);
            ((uint4*)Bh)[tid * 2]     = sh[tid * 2];
            ((uint4*)Bh)[tid * 2 + 1] = sh[tid * 2 + 1];
            ((uint4*)Bl)[tid * 2]     = sl[tid * 2];
            ((uint4*)Bl)[tid * 2 + 1] = sl[tid * 2 + 1];
        }
        __syncthreads();

        const int mb0 = w * 2, mb1 = w * 2 + 1;
        s16x8 a0h = *(const s16x8*)&Ah[(mb0 * 64 + lane) * 8];
        s16x8 a0l = *(const s16x8*)&Al[(mb0 * 64 + lane) * 8];
        s16x8 a1h = *(const s16x8*)&Ah[(mb1 * 64 + lane) * 8];
        s16x8 a1l = *(const s16x8*)&Al[(mb1 * 64 + lane) * 8];
#pragma unroll
        for (int nb = 0; nb < 8; ++nb) {
            s16x8 bh = *(const s16x8*)&Bh[(nb * 64 + lane) * 8];
            s16x8 bl = *(const s16x8*)&Bl[(nb * 64 + lane) * 8];
            acc[0][nb] = __builtin_amdgcn_mfma_f32_16x16x32_bf16(a0h, bh, acc[0][nb], 0, 0, 0);
            acc[0][nb] = __builtin_amdgcn_mfma_f32_16x16x32_bf16(a0h, bl, acc[0][nb], 0, 0, 0);
            acc[0][nb] = __builtin_amdgcn_mfma_f32_16x16x32_bf16(a0l, bh, acc[0][nb], 0, 0, 0);
            acc[1][nb] = __builtin_amdgcn_mfma_f32_16x16x32_bf16(a1h, bh, acc[1][nb], 0, 0, 0);
            acc[1][nb] = __builtin_amdgcn_mfma_f32_16x16x32_bf16(a1h, bl, acc[1][nb], 0, 0, 0);
            acc[1][nb] = __builtin_amdgcn_mfma_f32_16x16x32_bf16(a1l, bh, acc[1][nb], 0, 0, 0);
        }
        __syncthreads();
    }

    // epilogue: C/D layout col = lane&15, row = (lane>>4)*4 + reg  [m89/m91]
    const int col = lane & 15;
    const int rg4 = (lane >> 4) * 4;
#pragma unroll
    for (int mb = 0; mb < 2; ++mb) {
#pragma unroll
        for (int reg = 0; reg < 4; ++reg) {
            int gr = brow + (w * 2 + mb) * 16 + rg4 + reg;
            if (gr < N_NODES) {
                float dv = dinv[gr];
#pragma unroll
                for (int nb = 0; nb < 8; ++nb)
                    tab[(size_t)gr * H_F + nb * 16 + col] =
                        f2bf_rne(acc[mb][nb][reg] * dv);
            }
        }
    }
}

// ---------------- fused aggregate + mean + bias + relu (+ classifier) --------
// tab rows are bf16, pre-scaled by dinv. Per node:
//   o = relu( dinv[d] * (sum_edges tab[src] + tab[d]) / (cnt+1) + bias )
// Half-wave (32 lanes x 4 bf16 = 128-feat row) per node, 4-deep edge unroll.
// fp32 accumulate; only the gathered operand is bf16.

template <bool FUSE_OUT>
__global__ __launch_bounds__(256) void k_agg(const unsigned short* __restrict__ tab,
                                             const int* __restrict__ row_off,
                                             const int* __restrict__ cnt,
                                             const int* __restrict__ csr_src,
                                             const float* __restrict__ dinv,
                                             const float* __restrict__ bias,
                                             const float* __restrict__ Wc,
                                             const float* __restrict__ bc,
                                             float* __restrict__ outp) {
    const int node = blockIdx.x * 8 + (threadIdx.x >> 5);
    if (node >= N_NODES) return;
    const int sl = threadIdx.x & 31;
    const int co = sl * 4;             // bf16 feature base

    const int beg = row_off[node];
    const int c   = cnt[node];
    const int* ep = csr_src + beg;

    float4 acc = make_float4(0.f, 0.f, 0.f, 0.f);
    int k = 0;
    for (; k + 4 <= c; k += 4) {
        int s0 = ep[k], s1 = ep[k + 1], s2 = ep[k + 2], s3 = ep[k + 3];
        uint2 u0 = *(const uint2*)(tab + (size_t)s0 * H_F + co);
        uint2 u1 = *(const uint2*)(tab + (size_t)s1 * H_F + co);
        uint2 u2 = *(const uint2*)(tab + (size_t)s2 * H_F + co);
        uint2 u3 = *(const uint2*)(tab + (size_t)s3 * H_F + co);
        acc.x += __uint_as_float(u0.x << 16) + __uint_as_float(u1.x << 16)
               + __uint_as_float(u2.x << 16) + __uint_as_float(u3.x << 16);
        acc.y += __uint_as_float(u0.x & 0xFFFF0000u) + __uint_as_float(u1.x & 0xFFFF0000u)
               + __uint_as_float(u2.x & 0xFFFF0000u) + __uint_as_float(u3.x & 0xFFFF0000u);
        acc.z += __uint_as_float(u0.y << 16) + __uint_as_float(u1.y << 16)
               + __uint_as_float(u2.y << 16) + __uint_as_float(u3.y << 16);
        acc.w += __uint_as_float(u0.y & 0xFFFF0000u) + __uint_as_float(u1.y & 0xFFFF0000u)
               + __uint_as_float(u2.y & 0xFFFF0000u) + __uint_as_float(u3.y & 0xFFFF0000u);
    }
    for (; k < c; ++k) {
        int s0 = ep[k];
        uint2 u0 = *(const uint2*)(tab + (size_t)s0 * H_F + co);
        acc.x += __uint_as_float(u0.x << 16);
        acc.y += __uint_as_float(u0.x & 0xFFFF0000u);
        acc.z += __uint_as_float(u0.y << 16);
        acc.w += __uint_as_float(u0.y & 0xFFFF0000u);
    }
    // self term + scale + bias + relu
    uint2 us = *(const uint2*)(tab + (size_t)node * H_F + co);
    acc.x += __uint_as_float(us.x << 16);
    acc.y += __uint_as_float(us.x & 0xFFFF0000u);
    acc.z += __uint_as_float(us.y << 16);
    acc.w += __uint_as_float(us.y & 0xFFFF0000u);
    float s = dinv[node] / (float)(c + 1);
    float4 bv = *(const float4*)(bias + co);
    float4 o;
    o.x = fmaxf(fmaf(acc.x, s, bv.x), 0.f);
    o.y = fmaxf(fmaf(acc.y, s, bv.y), 0.f);
    o.z = fmaxf(fmaf(acc.z, s, bv.z), 0.f);
    o.w = fmaxf(fmaf(acc.w, s, bv.w), 0.f);

    if (!FUSE_OUT) {
        *(float4*)(outp + (size_t)node * H_F + co) = o;
    } else {
        float po[C_OUT];
#pragma unroll
        for (int cc = 0; cc < C_OUT; ++cc) {
            float t = o.x * Wc[(co + 0) * C_OUT + cc];
            t = fmaf(o.y, Wc[(co + 1) * C_OUT + cc], t);
            t = fmaf(o.z, Wc[(co + 2) * C_OUT + cc], t);
            po[cc] = fmaf(o.w, Wc[(co + 3) * C_OUT + cc], t);
        }
#pragma unroll
        for (int off = 16; off; off >>= 1)
#pragma unroll
            for (int cc = 0; cc < C_OUT; ++cc)
                po[cc] += __shfl_xor(po[cc], off, 64);   // offsets <32 stay in-half
        if (sl == 0) {
#pragma unroll
            for (int cc = 0; cc < C_OUT; ++cc)
                outp[(size_t)node * C_OUT + cc] = po[cc] + bc[cc];
        }
    }
}

// ---------------- launch ----------------

extern "C" void kernel_launch(void* const* d_in, const int* in_sizes, int n_in,
                              void* d_out, int out_size, void* d_ws, size_t ws_size,
                              hipStream_t stream) {
    const float* x  = (const float*)d_in[0];
    const int*   ei = (const int*)d_in[1];
    const float* W1 = (const float*)d_in[2];
    const float* b1 = (const float*)d_in[3];
    const float* W2 = (const float*)d_in[4];
    const float* b2 = (const float*)d_in[5];
    const float* Wc = (const float*)d_in[6];
    const float* bc = (const float*)d_in[7];
    const int* esrc = ei;
    const int* edst = ei + E_EDGES;

    char* ws = (char*)d_ws;
    int*   bcnt    = (int*)ws;                    ws += sizeof(int) * NBKT;
    int*   boff    = (int*)ws;                    ws += sizeof(int) * (NBKT + 1);
    int*   bcur    = (int*)ws;                    ws += sizeof(int) * NBKT;
    int*   cnt     = (int*)ws;                    ws += sizeof(int) * N_NODES;
    int*   row_off = (int*)ws;                    ws += sizeof(int) * N_NODES;
    float* dinv    = (float*)ws;                  ws += sizeof(float) * N_NODES;
    ws = (char*)(((size_t)ws + 15) & ~(size_t)15);
    int*   packed  = (int*)ws;                    ws += sizeof(int) * E_EDGES;
    int*   csr_src = (int*)ws;                    ws += sizeof(int) * E_EDGES;
    unsigned short* B1h = (unsigned short*)ws;    ws += sizeof(short) * IN_F * H_F;
    unsigned short* B1l = (unsigned short*)ws;    ws += sizeof(short) * IN_F * H_F;
    unsigned short* B2h = (unsigned short*)ws;    ws += sizeof(short) * H_F * H_F;
    unsigned short* B2l = (unsigned short*)ws;    ws += sizeof(short) * H_F * H_F;
    unsigned short* tabBF = (unsigned short*)ws;  ws += sizeof(short) * (size_t)N_NODES * H_F;
    float* h1      = (float*)ws;                  ws += sizeof(float) * (size_t)N_NODES * H_F;

    const int gE = (E_EDGES + 255) / 256;
    const int gAgg = (N_NODES + 7) / 8;
    const int gGemm = (N_NODES + 127) / 128;
    const int gConv = (IN_F * H_F + H_F * H_F + 255) / 256;

    // CSR build via coarse-bucket counting sort (graph fixed; rebuilt per call)
    hipMemsetAsync(bcnt, 0, sizeof(int) * NBKT, stream);
    k_bcount<<<gE, 256, 0, stream>>>(edst, bcnt);
    k_scanB<<<1, 1024, 0, stream>>>(bcnt, boff, bcur);
    k_passA<<<gE, 256, 0, stream>>>(esrc, edst, bcur, packed);
    k_passB<<<NBKT, 256, 0, stream>>>(packed, boff, cnt, row_off, dinv, csr_src);
    k_convB<<<gConv, 256, 0, stream>>>(W1, W2, B1h, B1l, B2h, B2l);

    // layer 1 (GEMM emits bf16 gather table, pre-scaled by dinv)
    k_gemm_mfma<IN_F><<<gGemm, 256, 0, stream>>>(x, B1h, B1l, dinv, tabBF);
    k_agg<false><<<gAgg, 256, 0, stream>>>(tabBF, row_off, cnt, csr_src, dinv, b1,
                                           nullptr, nullptr, h1);

    // layer 2 (+ fused classifier)
    k_gemm_mfma<H_F><<<gGemm, 256, 0, stream>>>(h1, B2h, B2l, dinv, tabBF);
    k_agg<true><<<gAgg, 256, 0, stream>>>(tabBF, row_off, cnt, csr_src, dinv, b2,
                                          Wc, bc, (float*)d_out);
}

// Round 11
// 172.846 us; speedup vs baseline: 3.0525x; 3.0525x over previous
//
#include <hip/hip_runtime.h>

#define N_NODES 50000
#define E_EDGES 800000
#define IN_F 256
#define H_F 128
#define C_OUT 10
#define NBKT ((N_NODES + 63) / 64)        // 782 coarse buckets (64 nodes each)
#define EPB 4096                          // edges per block in bhist/passA
#define NBLK ((E_EDGES + EPB - 1) / EPB)  // 196
static_assert(NBKT <= 1024, "scanB single block assumes <=1024 buckets");

typedef __attribute__((ext_vector_type(4))) float f32x4;
typedef __attribute__((ext_vector_type(8))) short s16x8;

__device__ __forceinline__ unsigned short f2bf_rne(float x) {
    unsigned u = __float_as_uint(x);
    u = (u + 0x7FFFu + ((u >> 16) & 1u)) >> 16;
    return (unsigned short)u;
}
__device__ __forceinline__ float bf2f(unsigned short h) {
    return __uint_as_float(((unsigned)h) << 16);
}

// ---------------- CSR build: coarse-bucket counting sort (LDS-aggregated) ----

// per-block LDS histogram -> one global add per touched bucket
__global__ __launch_bounds__(256) void k_bhist(const int* __restrict__ dst,
                                               int* __restrict__ bcnt) {
    __shared__ int h[NBKT];
    const int tid = threadIdx.x;
    for (int i = tid; i < NBKT; i += 256) h[i] = 0;
    __syncthreads();
    const int e0 = blockIdx.x * EPB + tid;
#pragma unroll
    for (int j = 0; j < EPB / 256; ++j) {
        int e = e0 + j * 256;
        if (e < E_EDGES) atomicAdd(&h[dst[e] >> 6], 1);
    }
    __syncthreads();
    for (int i = tid; i < NBKT; i += 256)
        if (h[i]) atomicAdd(&bcnt[i], h[i]);
}

// single-block exclusive scan of bucket counts; init bucket cursors
__global__ __launch_bounds__(1024) void k_scanB(const int* __restrict__ bcnt,
                                                int* __restrict__ boff,
                                                int* __restrict__ bcur) {
    __shared__ int sm[1024];
    int tid = threadIdx.x;
    int v = (tid < NBKT) ? bcnt[tid] : 0;
    sm[tid] = v;
    __syncthreads();
#pragma unroll
    for (int off = 1; off < 1024; off <<= 1) {
        int t = (tid >= off) ? sm[tid - off] : 0;
        __syncthreads();
        sm[tid] += t;
        __syncthreads();
    }
    if (tid < NBKT) {
        int ex = sm[tid] - v;
        boff[tid] = ex;
        bcur[tid] = ex;
    }
    if (tid == 0) boff[NBKT] = E_EDGES;
}

// pass A: LDS-aggregated scatter into coarse bucket regions.
// Per-edge atomic return comes from LDS; only one global atomic per
// (block, touched bucket) -> ~196 atomics per cursor address total.
__global__ __launch_bounds__(256) void k_passA(const int* __restrict__ src,
                                               const int* __restrict__ dst,
                                               int* __restrict__ bcur,
                                               int* __restrict__ packed) {
    __shared__ int h[NBKT];
    __shared__ int base[NBKT];
    const int tid = threadIdx.x;
    for (int i = tid; i < NBKT; i += 256) h[i] = 0;
    __syncthreads();
    const int e0 = blockIdx.x * EPB + tid;
    int lpos[EPB / 256], pv[EPB / 256];
    short bb[EPB / 256];
#pragma unroll
    for (int j = 0; j < EPB / 256; ++j) {
        int e = e0 + j * 256;
        if (e < E_EDGES) {
            int s = src[e], d = dst[e];
            bb[j] = (short)(d >> 6);
            pv[j] = (s << 6) | (d & 63);
            lpos[j] = atomicAdd(&h[d >> 6], 1);
        } else bb[j] = -1;
    }
    __syncthreads();
    for (int i = tid; i < NBKT; i += 256)
        if (h[i]) base[i] = atomicAdd(&bcur[i], h[i]);
    __syncthreads();
#pragma unroll
    for (int j = 0; j < EPB / 256; ++j)
        if (bb[j] >= 0) packed[base[bb[j]] + lpos[j]] = pv[j];
}

// pass B: per-bucket fine sort in LDS; emits csr_src plus cnt/row_off/dinv.
__global__ __launch_bounds__(256) void k_passB(const int* __restrict__ packed,
                                               const int* __restrict__ boff,
                                               int* __restrict__ cnt,
                                               int* __restrict__ row_off,
                                               float* __restrict__ dinv,
                                               int* __restrict__ csr_src) {
    __shared__ int hist[64], loff[64], lcur[64];
    const int b = blockIdx.x, tid = threadIdx.x;
    const int beg = boff[b], end = boff[b + 1];
    if (tid < 64) hist[tid] = 0;
    __syncthreads();
    for (int e = beg + tid; e < end; e += 256)
        atomicAdd(&hist[packed[e] & 63], 1);
    __syncthreads();
    if (tid == 0) {
        int run = 0;
#pragma unroll
        for (int i = 0; i < 64; ++i) { int t = hist[i]; loff[i] = run; lcur[i] = run; run += t; }
    }
    __syncthreads();
    if (tid < 64) {
        int node = b * 64 + tid;
        if (node < N_NODES) {
            int c = hist[tid];
            cnt[node] = c;
            dinv[node] = rsqrtf((float)(c + 1));
            row_off[node] = beg + loff[tid];
        }
    }
    for (int e = beg + tid; e < end; e += 256) {
        int p = packed[e];
        int pos = atomicAdd(&lcur[p & 63], 1);
        csr_src[beg + pos] = p >> 6;
    }
}

// ---------------- pre-pack W1/W2 into MFMA fragment-image (bf16 hi/lo) -------
// Fragment image: [kt][nb][lane][j] ushort, lane=(n&15)+16*((k&31)>>3), j=k&7.

__global__ __launch_bounds__(256) void k_convB(const float* __restrict__ W1,
                                               const float* __restrict__ W2,
                                               unsigned short* __restrict__ B1h,
                                               unsigned short* __restrict__ B1l,
                                               unsigned short* __restrict__ B2h,
                                               unsigned short* __restrict__ B2l) {
    int id = blockIdx.x * 256 + threadIdx.x;
    const float* W;
    unsigned short *Bh, *Bl;
    int k, n;
    if (id < IN_F * H_F) {
        W = W1; Bh = B1h; Bl = B1l;
        k = id >> 7; n = id & 127;
    } else {
        id -= IN_F * H_F;
        if (id >= H_F * H_F) return;
        W = W2; Bh = B2h; Bl = B2l;
        k = id >> 7; n = id & 127;
    }
    float x = W[(size_t)k * H_F + n];
    unsigned short h = f2bf_rne(x);
    unsigned short l = f2bf_rne(x - bf2f(h));
    int kt = k >> 5, kg = (k & 31) >> 3, j = k & 7;
    int lane = (n & 15) + 16 * kg, nb = n >> 4;
    size_t idx = (((size_t)kt * 8 + nb) * 64 + lane) * 8 + j;
    Bh[idx] = h;
    Bl[idx] = l;
}

// ---------------- MFMA GEMM: tab[M x 128] = bf16((A[M x K] @ W[K x 128])*dinv) --
// bf16x3 split (hi*hi + hi*lo + lo*hi), fp32 accumulate. 128x128 tile,
// 4 waves x (2 m-frags x 8 n-frags), BK=32. Output is the bf16 gather table.

template <int K>
__global__ __launch_bounds__(256) void k_gemm_mfma(const float* __restrict__ A,
                                                   const unsigned short* __restrict__ Bh_img,
                                                   const unsigned short* __restrict__ Bl_img,
                                                   const float* __restrict__ dinv,
                                                   unsigned short* __restrict__ tab) {
    __shared__ unsigned short Ah[8 * 64 * 8];   // [mb][lane][j]
    __shared__ unsigned short Al[8 * 64 * 8];
    __shared__ unsigned short Bh[8 * 64 * 8];   // [nb][lane][j]
    __shared__ unsigned short Bl[8 * 64 * 8];

    const int tid  = threadIdx.x;
    const int w    = tid >> 6;
    const int lane = tid & 63;
    const int brow = blockIdx.x * 128;

    const int ar  = tid >> 1;          // A-stage row 0..127
    const int akq = tid & 1;           // k-half (16 floats)
    const int arow_l = min(brow + ar, N_NODES - 1);
    const float* Arow = A + (size_t)arow_l * K;
    const int amb = ar >> 4;
    const int ar15 = ar & 15;

    f32x4 acc[2][8] = {};

    for (int kt = 0; kt < K; kt += 32) {
        // stage A: 4x float4 per thread, convert to bf16 hi/lo
#pragma unroll
        for (int i = 0; i < 4; ++i) {
            int k0 = akq * 16 + i * 4;           // 0..28, step 4
            float4 v = *(const float4*)(Arow + kt + k0);
            unsigned short h0 = f2bf_rne(v.x), h1 = f2bf_rne(v.y);
            unsigned short h2 = f2bf_rne(v.z), h3 = f2bf_rne(v.w);
            unsigned short l0 = f2bf_rne(v.x - bf2f(h0));
            unsigned short l1 = f2bf_rne(v.y - bf2f(h1));
            unsigned short l2 = f2bf_rne(v.z - bf2f(h2));
            unsigned short l3 = f2bf_rne(v.w - bf2f(h3));
            int kg = k0 >> 3, j0 = k0 & 7;       // j0 in {0,4}
            int idx = ((amb * 64) + ar15 + 16 * kg) * 8 + j0;
            *(uint2*)&Ah[idx] = make_uint2((unsigned)h0 | ((unsigned)h1 << 16),
                                           (unsigned)h2 | ((unsigned)h3 << 16));
            *(uint2*)&Al[idx] = make_uint2((unsigned)l0 | ((unsigned)l1 << 16),
                                           (unsigned)l2 | ((unsigned)l3 << 16));
        }
        // stage B: copy 8 KB hi + 8 KB lo from pre-packed image
        {
            const uint4* sh = (const uint4*)(Bh_img + (size_t)(kt >> 5) * 4096);
            const uint4* sl = (const uint4*)(Bl_img + (size_t)(kt >> 5) * 4096);
            ((uint4*)Bh)[tid * 2]     = sh[tid * 2];
            ((uint4*)Bh)[tid * 2 + 1] = sh[tid * 2 + 1];
            ((uint4*)Bl)[tid * 2]     = sl[tid * 2];
            ((uint4*)Bl)[tid * 2 + 1] = sl[tid * 2 + 1];
        }
        __syncthreads();

        const int mb0 = w * 2, mb1 = w * 2 + 1;
        s16x8 a0h = *(const s16x8*)&Ah[(mb0 * 64 + lane) * 8];
        s16x8 a0l = *(const s16x8*)&Al[(mb0 * 64 + lane) * 8];
        s16x8 a1h = *(const s16x8*)&Ah[(mb1 * 64 + lane) * 8];
        s16x8 a1l = *(const s16x8*)&Al[(mb1 * 64 + lane) * 8];
#pragma unroll
        for (int nb = 0; nb < 8; ++nb) {
            s16x8 bh = *(const s16x8*)&Bh[(nb * 64 + lane) * 8];
            s16x8 bl = *(const s16x8*)&Bl[(nb * 64 + lane) * 8];
            acc[0][nb] = __builtin_amdgcn_mfma_f32_16x16x32_bf16(a0h, bh, acc[0][nb], 0, 0, 0);
            acc[0][nb] = __builtin_amdgcn_mfma_f32_16x16x32_bf16(a0h, bl, acc[0][nb], 0, 0, 0);
            acc[0][nb] = __builtin_amdgcn_mfma_f32_16x16x32_bf16(a0l, bh, acc[0][nb], 0, 0, 0);
            acc[1][nb] = __builtin_amdgcn_mfma_f32_16x16x32_bf16(a1h, bh, acc[1][nb], 0, 0, 0);
            acc[1][nb] = __builtin_amdgcn_mfma_f32_16x16x32_bf16(a1h, bl, acc[1][nb], 0, 0, 0);
            acc[1][nb] = __builtin_amdgcn_mfma_f32_16x16x32_bf16(a1l, bh, acc[1][nb], 0, 0, 0);
        }
        __syncthreads();
    }

    // epilogue: C/D layout col = lane&15, row = (lane>>4)*4 + reg  [m89/m91]
    const int col = lane & 15;
    const int rg4 = (lane >> 4) * 4;
#pragma unroll
    for (int mb = 0; mb < 2; ++mb) {
#pragma unroll
        for (int reg = 0; reg < 4; ++reg) {
            int gr = brow + (w * 2 + mb) * 16 + rg4 + reg;
            if (gr < N_NODES) {
                float dv = dinv[gr];
#pragma unroll
                for (int nb = 0; nb < 8; ++nb)
                    tab[(size_t)gr * H_F + nb * 16 + col] =
                        f2bf_rne(acc[mb][nb][reg] * dv);
            }
        }
    }
}

// ---------------- fused aggregate + mean + bias + relu (+ classifier) --------
// tab rows are bf16, pre-scaled by dinv. Per node:
//   o = relu( dinv[d] * (sum_edges tab[src] + tab[d]) / (cnt+1) + bias )
// Half-wave (32 lanes x 4 bf16 = 128-feat row) per node, 4-deep edge unroll.
// fp32 accumulate; only the gathered operand is bf16.

template <bool FUSE_OUT>
__global__ __launch_bounds__(256) void k_agg(const unsigned short* __restrict__ tab,
                                             const int* __restrict__ row_off,
                                             const int* __restrict__ cnt,
                                             const int* __restrict__ csr_src,
                                             const float* __restrict__ dinv,
                                             const float* __restrict__ bias,
                                             const float* __restrict__ Wc,
                                             const float* __restrict__ bc,
                                             float* __restrict__ outp) {
    const int node = blockIdx.x * 8 + (threadIdx.x >> 5);
    if (node >= N_NODES) return;
    const int sl = threadIdx.x & 31;
    const int co = sl * 4;             // bf16 feature base

    const int beg = row_off[node];
    const int c   = cnt[node];
    const int* ep = csr_src + beg;

    float4 acc = make_float4(0.f, 0.f, 0.f, 0.f);
    int k = 0;
    for (; k + 4 <= c; k += 4) {
        int s0 = ep[k], s1 = ep[k + 1], s2 = ep[k + 2], s3 = ep[k + 3];
        uint2 u0 = *(const uint2*)(tab + (size_t)s0 * H_F + co);
        uint2 u1 = *(const uint2*)(tab + (size_t)s1 * H_F + co);
        uint2 u2 = *(const uint2*)(tab + (size_t)s2 * H_F + co);
        uint2 u3 = *(const uint2*)(tab + (size_t)s3 * H_F + co);
        acc.x += __uint_as_float(u0.x << 16) + __uint_as_float(u1.x << 16)
               + __uint_as_float(u2.x << 16) + __uint_as_float(u3.x << 16);
        acc.y += __uint_as_float(u0.x & 0xFFFF0000u) + __uint_as_float(u1.x & 0xFFFF0000u)
               + __uint_as_float(u2.x & 0xFFFF0000u) + __uint_as_float(u3.x & 0xFFFF0000u);
        acc.z += __uint_as_float(u0.y << 16) + __uint_as_float(u1.y << 16)
               + __uint_as_float(u2.y << 16) + __uint_as_float(u3.y << 16);
        acc.w += __uint_as_float(u0.y & 0xFFFF0000u) + __uint_as_float(u1.y & 0xFFFF0000u)
               + __uint_as_float(u2.y & 0xFFFF0000u) + __uint_as_float(u3.y & 0xFFFF0000u);
    }
    for (; k < c; ++k) {
        int s0 = ep[k];
        uint2 u0 = *(const uint2*)(tab + (size_t)s0 * H_F + co);
        acc.x += __uint_as_float(u0.x << 16);
        acc.y += __uint_as_float(u0.x & 0xFFFF0000u);
        acc.z += __uint_as_float(u0.y << 16);
        acc.w += __uint_as_float(u0.y & 0xFFFF0000u);
    }
    // self term + scale + bias + relu
    uint2 us = *(const uint2*)(tab + (size_t)node * H_F + co);
    acc.x += __uint_as_float(us.x << 16);
    acc.y += __uint_as_float(us.x & 0xFFFF0000u);
    acc.z += __uint_as_float(us.y << 16);
    acc.w += __uint_as_float(us.y & 0xFFFF0000u);
    float s = dinv[node] / (float)(c + 1);
    float4 bv = *(const float4*)(bias + co);
    float4 o;
    o.x = fmaxf(fmaf(acc.x, s, bv.x), 0.f);
    o.y = fmaxf(fmaf(acc.y, s, bv.y), 0.f);
    o.z = fmaxf(fmaf(acc.z, s, bv.z), 0.f);
    o.w = fmaxf(fmaf(acc.w, s, bv.w), 0.f);

    if (!FUSE_OUT) {
        *(float4*)(outp + (size_t)node * H_F + co) = o;
    } else {
        float po[C_OUT];
#pragma unroll
        for (int cc = 0; cc < C_OUT; ++cc) {
            float t = o.x * Wc[(co + 0) * C_OUT + cc];
            t = fmaf(o.y, Wc[(co + 1) * C_OUT + cc], t);
            t = fmaf(o.z, Wc[(co + 2) * C_OUT + cc], t);
            po[cc] = fmaf(o.w, Wc[(co + 3) * C_OUT + cc], t);
        }
#pragma unroll
        for (int off = 16; off; off >>= 1)
#pragma unroll
            for (int cc = 0; cc < C_OUT; ++cc)
                po[cc] += __shfl_xor(po[cc], off, 64);   // offsets <32 stay in-half
        if (sl == 0) {
#pragma unroll
            for (int cc = 0; cc < C_OUT; ++cc)
                outp[(size_t)node * C_OUT + cc] = po[cc] + bc[cc];
        }
    }
}

// ---------------- launch ----------------

extern "C" void kernel_launch(void* const* d_in, const int* in_sizes, int n_in,
                              void* d_out, int out_size, void* d_ws, size_t ws_size,
                              hipStream_t stream) {
    const float* x  = (const float*)d_in[0];
    const int*   ei = (const int*)d_in[1];
    const float* W1 = (const float*)d_in[2];
    const float* b1 = (const float*)d_in[3];
    const float* W2 = (const float*)d_in[4];
    const float* b2 = (const float*)d_in[5];
    const float* Wc = (const float*)d_in[6];
    const float* bc = (const float*)d_in[7];
    const int* esrc = ei;
    const int* edst = ei + E_EDGES;

    char* ws = (char*)d_ws;
    int*   bcnt    = (int*)ws;                    ws += sizeof(int) * NBKT;
    int*   boff    = (int*)ws;                    ws += sizeof(int) * (NBKT + 1);
    int*   bcur    = (int*)ws;                    ws += sizeof(int) * NBKT;
    int*   cnt     = (int*)ws;                    ws += sizeof(int) * N_NODES;
    int*   row_off = (int*)ws;                    ws += sizeof(int) * N_NODES;
    float* dinv    = (float*)ws;                  ws += sizeof(float) * N_NODES;
    ws = (char*)(((size_t)ws + 15) & ~(size_t)15);
    int*   packed  = (int*)ws;                    ws += sizeof(int) * E_EDGES;
    int*   csr_src = (int*)ws;                    ws += sizeof(int) * E_EDGES;
    unsigned short* B1h = (unsigned short*)ws;    ws += sizeof(short) * IN_F * H_F;
    unsigned short* B1l = (unsigned short*)ws;    ws += sizeof(short) * IN_F * H_F;
    unsigned short* B2h = (unsigned short*)ws;    ws += sizeof(short) * H_F * H_F;
    unsigned short* B2l = (unsigned short*)ws;    ws += sizeof(short) * H_F * H_F;
    unsigned short* tabBF = (unsigned short*)ws;  ws += sizeof(short) * (size_t)N_NODES * H_F;
    float* h1      = (float*)ws;                  ws += sizeof(float) * (size_t)N_NODES * H_F;

    const int gAgg = (N_NODES + 7) / 8;
    const int gGemm = (N_NODES + 127) / 128;
    const int gConv = (IN_F * H_F + H_F * H_F + 255) / 256;

    // CSR build via LDS-aggregated coarse-bucket counting sort
    hipMemsetAsync(bcnt, 0, sizeof(int) * NBKT, stream);
    k_bhist<<<NBLK, 256, 0, stream>>>(edst, bcnt);
    k_scanB<<<1, 1024, 0, stream>>>(bcnt, boff, bcur);
    k_passA<<<NBLK, 256, 0, stream>>>(esrc, edst, bcur, packed);
    k_passB<<<NBKT, 256, 0, stream>>>(packed, boff, cnt, row_off, dinv, csr_src);
    k_convB<<<gConv, 256, 0, stream>>>(W1, W2, B1h, B1l, B2h, B2l);

    // layer 1 (GEMM emits bf16 gather table, pre-scaled by dinv)
    k_gemm_mfma<IN_F><<<gGemm, 256, 0, stream>>>(x, B1h, B1l, dinv, tabBF);
    k_agg<false><<<gAgg, 256, 0, stream>>>(tabBF, row_off, cnt, csr_src, dinv, b1,
                                           nullptr, nullptr, h1);

    // layer 2 (+ fused classifier)
    k_gemm_mfma<H_F><<<gGemm, 256, 0, stream>>>(h1, B2h, B2l, dinv, tabBF);
    k_agg<true><<<gAgg, 256, 0, stream>>>(tabBF, row_off, cnt, csr_src, dinv, b2,
                                          Wc, bc, (float*)d_out);
}